// Round 1
// baseline (60.037 us; speedup 1.0000x reference)
//
#include <hip/hip_runtime.h>
#include <math.h>

#define S_IMG 160
#define NPIX (S_IMG * S_IMG)      // 25600
#define NF 4096
#define NCHUNK 32
#define FPC (NF / NCHUNK)         // 128 faces per chunk
#define TPB 256
#define PPT 4                     // pixels per thread
#define PIXBLKS (NPIX / (TPB * PPT))  // 25

// ---- projection constants (hardcoded from reference) ----
// ROT = [[eps,0,1],[0,1,0],[-1,0,eps]], eps = cos(pi/2) as f32
#define ROT_EPS 6.123234e-17f
#define CAM_Z 2.732f
#define VIEW_TAN 0.5773502691896258f

__device__ __forceinline__ float2 project_vert(const float* __restrict__ v, int i) {
    float x = v[3 * i], y = v[3 * i + 1], z = v[3 * i + 2];
    float vx = fmaf(ROT_EPS, x, z);
    float vy = y;
    float vz = fmaf(ROT_EPS, z, -x) + CAM_Z;
    float denom = vz * VIEW_TAN;
    float ix = vx / denom;
    float iy = vy / denom;
    return make_float2((ix + 1.0f) * (S_IMG * 0.5f), (iy + 1.0f) * (S_IMG * 0.5f));
}

// Per face: 9 edge coefficients (A*px + B*py + C == edge_dist * sign(area)),
// invalid faces -> A=B=0, C=-1e30 so that factor = 1/(1+exp(dmin)) == 1.
__global__ void face_setup(const float* __restrict__ verts, const int* __restrict__ faces,
                           float* __restrict__ fd, int nF) {
    int f = blockIdx.x * blockDim.x + threadIdx.x;
    if (f >= nF) return;
    int i0 = faces[3 * f], i1 = faces[3 * f + 1], i2 = faces[3 * f + 2];
    float2 a = project_vert(verts, i0);
    float2 b = project_vert(verts, i1);
    float2 c = project_vert(verts, i2);
    float area = (b.x - a.x) * (c.y - a.y) - (b.y - a.y) * (c.x - a.x);
    float sg = (area >= 0.0f) ? 1.0f : -1.0f;
    bool valid = fabsf(area) > 1e-6f;

    float o[12];
    float2 p0s[3] = {a, b, c};
    float2 p1s[3] = {b, c, a};
#pragma unroll
    for (int e = 0; e < 3; ++e) {
        float dx = p1s[e].x - p0s[e].x;
        float dy = p1s[e].y - p0s[e].y;
        float L = sqrtf(dx * dx + dy * dy) + 1e-8f;
        float s = sg / L;
        o[3 * e + 0] = valid ? (-dy * s) : 0.0f;
        o[3 * e + 1] = valid ? (dx * s) : 0.0f;
        o[3 * e + 2] = valid ? ((dy * p0s[e].x - dx * p0s[e].y) * s) : -1e30f;
    }
    o[9] = o[10] = o[11] = 0.0f;

    float4* dst = (float4*)(fd + (size_t)f * 12);
    dst[0] = make_float4(o[0], o[1], o[2], o[3]);
    dst[1] = make_float4(o[4], o[5], o[6], o[7]);
    dst[2] = make_float4(o[8], o[9], o[10], o[11]);
}

// grid = (PIXBLKS, NCHUNK). Each block stages FPC faces into LDS and
// accumulates the partial product of (1 - cov) for its pixels over the chunk.
__global__ void __launch_bounds__(TPB) cover_kernel(const float* __restrict__ fd,
                                                    float* __restrict__ partials) {
    __shared__ float lds[FPC * 12];
    int tid = threadIdx.x;
    int chunk = blockIdx.y;

    // stage: first FPC threads load one face (12 floats = 3x float4) each
    if (tid < FPC) {
        const float4* src = (const float4*)(fd + (size_t)(chunk * FPC + tid) * 12);
        float4* dst = (float4*)(lds + tid * 12);
        dst[0] = src[0];
        dst[1] = src[1];
        dst[2] = src[2];
    }
    __syncthreads();

    int pbase = blockIdx.x * (TPB * PPT) + tid;
    float px[PPT], py[PPT], prod[PPT];
#pragma unroll
    for (int i = 0; i < PPT; ++i) {
        int p = pbase + i * TPB;
        px[i] = (float)(p % S_IMG) + 0.5f;
        py[i] = (float)(p / S_IMG) + 0.5f;
        prod[i] = 1.0f;
    }

    for (int j = 0; j < FPC; ++j) {
        float4 c0 = *(const float4*)(lds + j * 12);
        float4 c1 = *(const float4*)(lds + j * 12 + 4);
        float4 c2 = *(const float4*)(lds + j * 12 + 8);
        // A1 B1 C1 | A2 B2 C2 | A3 B3 C3 = c0.x c0.y c0.z | c0.w c1.x c1.y | c1.z c1.w c2.x
#pragma unroll
        for (int i = 0; i < PPT; ++i) {
            float d1 = fmaf(c0.x, px[i], fmaf(c0.y, py[i], c0.z));
            float d2 = fmaf(c0.w, px[i], fmaf(c1.x, py[i], c1.y));
            float d3 = fmaf(c1.z, px[i], fmaf(c1.w, py[i], c2.x));
            float dmin = fminf(d1, fminf(d2, d3));
            // factor = 1 - sigmoid(dmin) = 1/(1+exp(dmin))
            float e = __expf(dmin);
            prod[i] *= __builtin_amdgcn_rcpf(1.0f + e);
        }
    }

#pragma unroll
    for (int i = 0; i < PPT; ++i) {
        partials[(size_t)chunk * NPIX + pbase + i * TPB] = prod[i];
    }
}

// Multiply the NCHUNK partials per pixel (in chunk order), write image,
// and produce per-block partial sums of squared error (deterministic).
__global__ void __launch_bounds__(256) finish_kernel(const float* __restrict__ partials,
                                                     const float* __restrict__ img_ref,
                                                     float* __restrict__ out,
                                                     float* __restrict__ bsums) {
    int p = blockIdx.x * 256 + threadIdx.x;
    float prod = 1.0f;
#pragma unroll
    for (int c = 0; c < NCHUNK; ++c) prod *= partials[(size_t)c * NPIX + p];
    float img = 1.0f - prod;
    out[p] = img;
    float d = img - img_ref[p];
    float sq = d * d;
#pragma unroll
    for (int off = 32; off > 0; off >>= 1) sq += __shfl_down(sq, off);
    __shared__ float red[4];
    int lane = threadIdx.x & 63;
    int wid = threadIdx.x >> 6;
    if (lane == 0) red[wid] = sq;
    __syncthreads();
    if (threadIdx.x == 0) bsums[blockIdx.x] = (red[0] + red[1]) + (red[2] + red[3]);
}

__global__ void loss_kernel(const float* __restrict__ bsums, float* __restrict__ loss_out,
                            int nblocks) {
    int t = threadIdx.x;
    float v = 0.0f;
    if (t < nblocks) v = bsums[t];
    if (t + 64 < nblocks) v += bsums[t + 64];
#pragma unroll
    for (int off = 32; off > 0; off >>= 1) v += __shfl_down(v, off);
    if (t == 0) loss_out[0] = v;
}

extern "C" void kernel_launch(void* const* d_in, const int* in_sizes, int n_in,
                              void* d_out, int out_size, void* d_ws, size_t ws_size,
                              hipStream_t stream) {
    const float* verts = (const float*)d_in[0];
    const int* faces = (const int*)d_in[1];
    const float* img_ref = (const float*)d_in[2];
    float* out = (float*)d_out;

    float* fd = (float*)d_ws;                 // NF*12 floats   = 196,608 B
    float* partials = fd + (size_t)NF * 12;   // NCHUNK*NPIX f  = 3,276,800 B
    float* bsums = partials + (size_t)NCHUNK * NPIX;  // 100 floats

    int nF = in_sizes[1] / 3;  // 4096

    face_setup<<<(nF + 255) / 256, 256, 0, stream>>>(verts, faces, fd, nF);
    cover_kernel<<<dim3(PIXBLKS, NCHUNK), TPB, 0, stream>>>(fd, partials);
    finish_kernel<<<NPIX / 256, 256, 0, stream>>>(partials, img_ref, out, bsums);
    loss_kernel<<<1, 64, 0, stream>>>(bsums, out + NPIX, NPIX / 256);
}

// Round 2
// 49.731 us; speedup vs baseline: 1.2072x; 1.2072x over previous
//
#include <hip/hip_runtime.h>
#include <math.h>

#define S_IMG 160
#define NPIX (S_IMG * S_IMG)      // 25600
#define NF 4096
#define INV_LN2 1.4426950408889634f

// ---- projection constants (hardcoded from reference) ----
// ROT = [[eps,0,1],[0,1,0],[-1,0,eps]], eps = cos(pi/2) as f32
#define ROT_EPS 6.123234e-17f
#define CAM_Z 2.732f
#define VIEW_TAN 0.5773502691896258f

#if __has_builtin(__builtin_amdgcn_exp2f)
#define EXP2F(x) __builtin_amdgcn_exp2f(x)
#else
#define EXP2F(x) exp2f(x)
#endif

__device__ __forceinline__ float2 project_vert(const float* __restrict__ v, int i) {
    float x = v[3 * i], y = v[3 * i + 1], z = v[3 * i + 2];
    float vx = fmaf(ROT_EPS, x, z);
    float vy = y;
    float vz = fmaf(ROT_EPS, z, -x) + CAM_Z;
    float denom = vz * VIEW_TAN;
    return make_float2((vx / denom + 1.0f) * (S_IMG * 0.5f),
                       (vy / denom + 1.0f) * (S_IMG * 0.5f));
}

// One wave per block. Pixel tile: 32 cols x 8 rows (4 rows per thread, same
// column -> A*px+C shared across the 4 pixels). Face chunk of FPC faces is
// set up in-kernel (1 face per lane) into LDS; inner-loop reads are
// wave-uniform broadcasts. Coefficients are pre-scaled by 1/ln2 so the
// sigmoid exponent uses v_exp_f32 (2^x) directly.
// Accumulate P = prod(1 + 2^d); factor per chunk = rcp(P). P -> inf is fine
// (rcp gives 0 == fully covered).
template <int FPC>
__global__ void __launch_bounds__(64) cover_kernel(const float* __restrict__ verts,
                                                   const int* __restrict__ faces,
                                                   float* __restrict__ partials) {
    __shared__ float4 lds[FPC * 3];
    const int tid = threadIdx.x;
    const int chunk = blockIdx.y;

    for (int f = tid; f < FPC; f += 64) {
        int gf = chunk * FPC + f;
        int i0 = faces[3 * gf], i1 = faces[3 * gf + 1], i2 = faces[3 * gf + 2];
        float2 a = project_vert(verts, i0);
        float2 b = project_vert(verts, i1);
        float2 c = project_vert(verts, i2);
        float area = (b.x - a.x) * (c.y - a.y) - (b.y - a.y) * (c.x - a.x);
        float sg = (area >= 0.0f) ? 1.0f : -1.0f;
        bool valid = fabsf(area) > 1e-6f;

        float o[9];
        float2 p0s[3] = {a, b, c};
        float2 p1s[3] = {b, c, a};
#pragma unroll
        for (int e = 0; e < 3; ++e) {
            float dx = p1s[e].x - p0s[e].x;
            float dy = p1s[e].y - p0s[e].y;
            float L = sqrtf(dx * dx + dy * dy) + 1e-8f;
            float s = sg * INV_LN2 / L;   // fold log2(e) into the coefficients
            o[3 * e + 0] = valid ? (-dy * s) : 0.0f;
            o[3 * e + 1] = valid ? (dx * s) : 0.0f;
            o[3 * e + 2] = valid ? ((dy * p0s[e].x - dx * p0s[e].y) * s) : -1e30f;
        }
        lds[f * 3 + 0] = make_float4(o[0], o[1], o[2], o[3]);
        lds[f * 3 + 1] = make_float4(o[4], o[5], o[6], o[7]);
        lds[f * 3 + 2] = make_float4(o[8], 0.0f, 0.0f, 0.0f);
    }
    __syncthreads();

    // pixel assignment: 5 x-tiles (32 cols) x 20 y-tiles (8 rows)
    const int xt = blockIdx.x % 5;
    const int yt = blockIdx.x / 5;
    const int col = xt * 32 + (tid & 31);
    const int row0 = yt * 8 + (tid >> 5) * 4;
    const float px = (float)col + 0.5f;
    const float py0 = (float)row0 + 0.5f;
    const float py1 = py0 + 1.0f, py2 = py0 + 2.0f, py3 = py0 + 3.0f;

    float P0 = 1.0f, P1 = 1.0f, P2 = 1.0f, P3 = 1.0f;

    for (int j = 0; j < FPC; ++j) {
        float4 c0 = lds[3 * j];
        float4 c1 = lds[3 * j + 1];
        float4 c2 = lds[3 * j + 2];
        // edges: (A1,B1,C1)=(c0.x,c0.y,c0.z) (A2,B2,C2)=(c0.w,c1.x,c1.y)
        //        (A3,B3,C3)=(c1.z,c1.w,c2.x)
        float b1 = fmaf(c0.x, px, c0.z);
        float b2 = fmaf(c0.w, px, c1.y);
        float b3 = fmaf(c1.z, px, c2.x);
        {
            float d1 = fmaf(c0.y, py0, b1), d2 = fmaf(c1.x, py0, b2), d3 = fmaf(c1.w, py0, b3);
            float e = EXP2F(fminf(fminf(d1, d2), d3));
            P0 = fmaf(P0, e, P0);
        }
        {
            float d1 = fmaf(c0.y, py1, b1), d2 = fmaf(c1.x, py1, b2), d3 = fmaf(c1.w, py1, b3);
            float e = EXP2F(fminf(fminf(d1, d2), d3));
            P1 = fmaf(P1, e, P1);
        }
        {
            float d1 = fmaf(c0.y, py2, b1), d2 = fmaf(c1.x, py2, b2), d3 = fmaf(c1.w, py2, b3);
            float e = EXP2F(fminf(fminf(d1, d2), d3));
            P2 = fmaf(P2, e, P2);
        }
        {
            float d1 = fmaf(c0.y, py3, b1), d2 = fmaf(c1.x, py3, b2), d3 = fmaf(c1.w, py3, b3);
            float e = EXP2F(fminf(fminf(d1, d2), d3));
            P3 = fmaf(P3, e, P3);
        }
    }

    size_t base = (size_t)chunk * NPIX + (size_t)row0 * S_IMG + col;
    partials[base] = __builtin_amdgcn_rcpf(P0);
    partials[base + S_IMG] = __builtin_amdgcn_rcpf(P1);
    partials[base + 2 * S_IMG] = __builtin_amdgcn_rcpf(P2);
    partials[base + 3 * S_IMG] = __builtin_amdgcn_rcpf(P3);
}

// Multiply the NCHUNK partials per pixel (chunk order), write image,
// per-block partial sums of squared error (deterministic tree).
template <int NCHUNK>
__global__ void __launch_bounds__(256) finish_kernel(const float* __restrict__ partials,
                                                     const float* __restrict__ img_ref,
                                                     float* __restrict__ out,
                                                     float* __restrict__ bsums) {
    int p = blockIdx.x * 256 + threadIdx.x;
    float prod = 1.0f;
#pragma unroll
    for (int c = 0; c < NCHUNK; ++c) prod *= partials[(size_t)c * NPIX + p];
    float img = 1.0f - prod;
    out[p] = img;
    float d = img - img_ref[p];
    float sq = d * d;
#pragma unroll
    for (int off = 32; off > 0; off >>= 1) sq += __shfl_down(sq, off);
    __shared__ float red[4];
    int lane = threadIdx.x & 63;
    int wid = threadIdx.x >> 6;
    if (lane == 0) red[wid] = sq;
    __syncthreads();
    if (threadIdx.x == 0) bsums[blockIdx.x] = (red[0] + red[1]) + (red[2] + red[3]);
}

__global__ void loss_kernel(const float* __restrict__ bsums, float* __restrict__ loss_out,
                            int nblocks) {
    int t = threadIdx.x;
    float v = 0.0f;
    if (t < nblocks) v = bsums[t];
    if (t + 64 < nblocks) v += bsums[t + 64];
#pragma unroll
    for (int off = 32; off > 0; off >>= 1) v += __shfl_down(v, off);
    if (t == 0) loss_out[0] = v;
}

extern "C" void kernel_launch(void* const* d_in, const int* in_sizes, int n_in,
                              void* d_out, int out_size, void* d_ws, size_t ws_size,
                              hipStream_t stream) {
    const float* verts = (const float*)d_in[0];
    const int* faces = (const int*)d_in[1];
    const float* img_ref = (const float*)d_in[2];
    float* out = (float*)d_out;

    float* partials = (float*)d_ws;

    size_t need64 = (size_t)64 * NPIX * sizeof(float) + 1024;
    if (ws_size >= need64) {
        constexpr int NCHUNK = 64;  // 64 faces per chunk
        float* bsums = partials + (size_t)NCHUNK * NPIX;
        cover_kernel<NF / NCHUNK><<<dim3(100, NCHUNK), 64, 0, stream>>>(verts, faces, partials);
        finish_kernel<NCHUNK><<<NPIX / 256, 256, 0, stream>>>(partials, img_ref, out, bsums);
        loss_kernel<<<1, 64, 0, stream>>>(bsums, out + NPIX, NPIX / 256);
    } else {
        constexpr int NCHUNK = 32;
        float* bsums = partials + (size_t)NCHUNK * NPIX;
        cover_kernel<NF / NCHUNK><<<dim3(100, NCHUNK), 64, 0, stream>>>(verts, faces, partials);
        finish_kernel<NCHUNK><<<NPIX / 256, 256, 0, stream>>>(partials, img_ref, out, bsums);
        loss_kernel<<<1, 64, 0, stream>>>(bsums, out + NPIX, NPIX / 256);
    }
}

// Round 3
// 48.305 us; speedup vs baseline: 1.2429x; 1.0295x over previous
//
#include <hip/hip_runtime.h>
#include <math.h>

#define S_IMG 160
#define NPIX (S_IMG * S_IMG)      // 25600
#define NF 4096
#define NTILE 100                 // 10 x 10 tiles of 16x16 pixels
#define MAXCH 64                  // worst case 4096/64 chunks per tile
#define INV_LN2 1.4426950408889634f
#define CULL_THRESH -25.0f        // e = 2^d < 2^-25  =>  factor == 1.0f exactly

// ---- projection constants (hardcoded from reference) ----
#define ROT_EPS 6.123234e-17f
#define CAM_Z 2.732f
#define VIEW_TAN 0.5773502691896258f

#if __has_builtin(__builtin_amdgcn_exp2f)
#define EXP2F(x) __builtin_amdgcn_exp2f(x)
#else
#define EXP2F(x) exp2f(x)
#endif

__device__ __forceinline__ float2 project_vert(const float* __restrict__ v, int i) {
    float x = v[3 * i], y = v[3 * i + 1], z = v[3 * i + 2];
    float vx = fmaf(ROT_EPS, x, z);
    float vy = y;
    float vz = fmaf(ROT_EPS, z, -x) + CAM_Z;
    float denom = vz * VIEW_TAN;
    return make_float2((vx / denom + 1.0f) * (S_IMG * 0.5f),
                       (vy / denom + 1.0f) * (S_IMG * 0.5f));
}

// Per face: edge coefficients scaled by log2(e) so the kernel uses 2^x.
// fd[f*12]  = A1 B1 C1 | A2 B2 C2 | A3 B3 C3 | pad pad pad
// cd[f*12]  = A1 B1 C1adj | ... (Cadj = C + (|A|+|B|)*7.5 : rect upper bound helper)
// invalid faces: A=B=0, C=Cadj=-1e30 -> e==0 in cover, culled everywhere.
__global__ void face_setup(const float* __restrict__ verts, const int* __restrict__ faces,
                           float* __restrict__ fd, float* __restrict__ cd, int nF) {
    int f = blockIdx.x * blockDim.x + threadIdx.x;
    if (f >= nF) return;
    int i0 = faces[3 * f], i1 = faces[3 * f + 1], i2 = faces[3 * f + 2];
    float2 a = project_vert(verts, i0);
    float2 b = project_vert(verts, i1);
    float2 c = project_vert(verts, i2);
    float area = (b.x - a.x) * (c.y - a.y) - (b.y - a.y) * (c.x - a.x);
    float sg = (area >= 0.0f) ? 1.0f : -1.0f;
    bool valid = fabsf(area) > 1e-6f;

    float o[9], u[9];
    float2 p0s[3] = {a, b, c};
    float2 p1s[3] = {b, c, a};
#pragma unroll
    for (int e = 0; e < 3; ++e) {
        float dx = p1s[e].x - p0s[e].x;
        float dy = p1s[e].y - p0s[e].y;
        float L = sqrtf(dx * dx + dy * dy) + 1e-8f;
        float s = sg * INV_LN2 / L;
        float A = valid ? (-dy * s) : 0.0f;
        float B = valid ? (dx * s) : 0.0f;
        float C = valid ? ((dy * p0s[e].x - dx * p0s[e].y) * s) : -1e30f;
        o[3 * e + 0] = A;
        o[3 * e + 1] = B;
        o[3 * e + 2] = C;
        u[3 * e + 0] = A;
        u[3 * e + 1] = B;
        u[3 * e + 2] = valid ? fmaf(fabsf(A) + fabsf(B), 7.5f, C) : -1e30f;
    }
    float4* df = (float4*)(fd + (size_t)f * 12);
    df[0] = make_float4(o[0], o[1], o[2], o[3]);
    df[1] = make_float4(o[4], o[5], o[6], o[7]);
    df[2] = make_float4(o[8], 0.0f, 0.0f, 0.0f);
    float4* dc = (float4*)(cd + (size_t)f * 12);
    dc[0] = make_float4(u[0], u[1], u[2], u[3]);
    dc[1] = make_float4(u[4], u[5], u[6], u[7]);
    dc[2] = make_float4(u[8], 0.0f, 0.0f, 0.0f);
}

// One wave per tile. Sequential 64-face rounds with ballot compaction:
// deterministic, face-order-preserving per-tile survivor lists.
__global__ void __launch_bounds__(64) cull_kernel(const float* __restrict__ cd,
                                                  int* __restrict__ list,
                                                  int* __restrict__ counts) {
    const int t = blockIdx.x;
    const int lane = threadIdx.x;
    const float cx = (float)((t % 10) * 16) + 8.0f;
    const float cy = (float)((t / 10) * 16) + 8.0f;
    int base = 0;
    for (int r = 0; r < NF / 64; ++r) {
        int f = r * 64 + lane;
        const float4* q = (const float4*)(cd + (size_t)f * 12);
        float4 q0 = q[0], q1 = q[1], q2 = q[2];
        float u1 = fmaf(q0.x, cx, fmaf(q0.y, cy, q0.z));
        float u2 = fmaf(q0.w, cx, fmaf(q1.x, cy, q1.y));
        float u3 = fmaf(q1.z, cx, fmaf(q1.w, cy, q2.x));
        bool pred = fminf(fminf(u1, u2), u3) >= CULL_THRESH;
        unsigned long long mask = __ballot(pred);
        int prefix = __popcll(mask & ((1ull << lane) - 1ull));
        if (pred) list[(size_t)t * NF + base + prefix] = f;
        base += __popcll(mask);
    }
    if (lane == 0) counts[t] = base;
}

// grid = (NTILE, MAXCH). Block (t,k) handles survivors [64k, 64k+64) of tile t.
// Empty chunks exit immediately. 16x16 pixel tile, 1 wave, 4 rows/thread.
__global__ void __launch_bounds__(64) cover_kernel(const float* __restrict__ fd,
                                                   const int* __restrict__ list,
                                                   const int* __restrict__ counts,
                                                   float* __restrict__ partials) {
    const int t = blockIdx.x;
    const int k = blockIdx.y;
    const int cnt = counts[t];
    if (k * 64 >= cnt) return;

    __shared__ float4 lds[64 * 3];
    const int lane = threadIdx.x;
    int i = k * 64 + lane;
    if (i < cnt) {
        int f = list[(size_t)t * NF + i];
        const float4* src = (const float4*)(fd + (size_t)f * 12);
        lds[lane * 3 + 0] = src[0];
        lds[lane * 3 + 1] = src[1];
        lds[lane * 3 + 2] = src[2];
    } else {
        lds[lane * 3 + 0] = make_float4(0.0f, 0.0f, -1e30f, 0.0f);
        lds[lane * 3 + 1] = make_float4(0.0f, -1e30f, 0.0f, 0.0f);
        lds[lane * 3 + 2] = make_float4(-1e30f, 0.0f, 0.0f, 0.0f);
    }
    __syncthreads();

    const int col = (t % 10) * 16 + (lane & 15);
    const int row0 = (t / 10) * 16 + (lane >> 4) * 4;
    const float px = (float)col + 0.5f;
    const float py0 = (float)row0 + 0.5f;
    const float py1 = py0 + 1.0f, py2 = py0 + 2.0f, py3 = py0 + 3.0f;

    float P0 = 1.0f, P1 = 1.0f, P2 = 1.0f, P3 = 1.0f;
    for (int j = 0; j < 64; ++j) {
        float4 c0 = lds[3 * j];
        float4 c1 = lds[3 * j + 1];
        float4 c2 = lds[3 * j + 2];
        float b1 = fmaf(c0.x, px, c0.z);
        float b2 = fmaf(c0.w, px, c1.y);
        float b3 = fmaf(c1.z, px, c2.x);
        {
            float d1 = fmaf(c0.y, py0, b1), d2 = fmaf(c1.x, py0, b2), d3 = fmaf(c1.w, py0, b3);
            float e = EXP2F(fminf(fminf(d1, d2), d3));
            P0 = fmaf(P0, e, P0);
        }
        {
            float d1 = fmaf(c0.y, py1, b1), d2 = fmaf(c1.x, py1, b2), d3 = fmaf(c1.w, py1, b3);
            float e = EXP2F(fminf(fminf(d1, d2), d3));
            P1 = fmaf(P1, e, P1);
        }
        {
            float d1 = fmaf(c0.y, py2, b1), d2 = fmaf(c1.x, py2, b2), d3 = fmaf(c1.w, py2, b3);
            float e = EXP2F(fminf(fminf(d1, d2), d3));
            P2 = fmaf(P2, e, P2);
        }
        {
            float d1 = fmaf(c0.y, py3, b1), d2 = fmaf(c1.x, py3, b2), d3 = fmaf(c1.w, py3, b3);
            float e = EXP2F(fminf(fminf(d1, d2), d3));
            P3 = fmaf(P3, e, P3);
        }
    }

    // within-tile pixel index = row_local*16 + col_local
    size_t idx = ((size_t)t * MAXCH + k) * 256 + (lane >> 4) * 64 + (lane & 15);
    partials[idx] = __builtin_amdgcn_rcpf(P0);
    partials[idx + 16] = __builtin_amdgcn_rcpf(P1);
    partials[idx + 32] = __builtin_amdgcn_rcpf(P2);
    partials[idx + 48] = __builtin_amdgcn_rcpf(P3);
}

// One block per tile (256 threads = 256 pixels). Multiplies only the live
// chunk layers (count-driven -> never reads unwritten/poisoned partials).
__global__ void __launch_bounds__(256) finish_kernel(const float* __restrict__ partials,
                                                     const int* __restrict__ counts,
                                                     const float* __restrict__ img_ref,
                                                     float* __restrict__ out,
                                                     float* __restrict__ bsums) {
    const int t = blockIdx.x;
    const int tid = threadIdx.x;
    const int nk = (counts[t] + 63) >> 6;
    float prod = 1.0f;
    for (int k = 0; k < nk; ++k) prod *= partials[((size_t)t * MAXCH + k) * 256 + tid];
    float img = 1.0f - prod;
    int col = (t % 10) * 16 + (tid & 15);
    int row = (t / 10) * 16 + (tid >> 4);
    int p = row * S_IMG + col;
    out[p] = img;
    float d = img - img_ref[p];
    float sq = d * d;
#pragma unroll
    for (int off = 32; off > 0; off >>= 1) sq += __shfl_down(sq, off);
    __shared__ float red[4];
    int lane = tid & 63;
    int wid = tid >> 6;
    if (lane == 0) red[wid] = sq;
    __syncthreads();
    if (tid == 0) bsums[t] = (red[0] + red[1]) + (red[2] + red[3]);
}

__global__ void loss_kernel(const float* __restrict__ bsums, float* __restrict__ loss_out,
                            int nblocks) {
    int t = threadIdx.x;
    float v = 0.0f;
    if (t < nblocks) v = bsums[t];
    if (t + 64 < nblocks) v += bsums[t + 64];
#pragma unroll
    for (int off = 32; off > 0; off >>= 1) v += __shfl_down(v, off);
    if (t == 0) loss_out[0] = v;
}

extern "C" void kernel_launch(void* const* d_in, const int* in_sizes, int n_in,
                              void* d_out, int out_size, void* d_ws, size_t ws_size,
                              hipStream_t stream) {
    const float* verts = (const float*)d_in[0];
    const int* faces = (const int*)d_in[1];
    const float* img_ref = (const float*)d_in[2];
    float* out = (float*)d_out;

    // workspace layout (all 16B aligned)
    float* fd = (float*)d_ws;                          // NF*12 floats
    float* cd = fd + (size_t)NF * 12;                  // NF*12 floats
    int* list = (int*)(cd + (size_t)NF * 12);          // NTILE*NF ints
    int* counts = list + (size_t)NTILE * NF;           // NTILE ints (+pad)
    float* partials = (float*)(counts + 128);          // NTILE*MAXCH*256 floats
    float* bsums = partials + (size_t)NTILE * MAXCH * 256;  // NTILE floats

    int nF = in_sizes[1] / 3;  // 4096

    face_setup<<<(nF + 255) / 256, 256, 0, stream>>>(verts, faces, fd, cd, nF);
    cull_kernel<<<NTILE, 64, 0, stream>>>(cd, list, counts);
    cover_kernel<<<dim3(NTILE, MAXCH), 64, 0, stream>>>(fd, list, counts, partials);
    finish_kernel<<<NTILE, 256, 0, stream>>>(partials, counts, img_ref, out, bsums);
    loss_kernel<<<1, 64, 0, stream>>>(bsums, out + NPIX, NTILE);
}